// Round 4
// baseline (1724.813 us; speedup 1.0000x reference)
//
#include <hip/hip_runtime.h>
#include <hip/hip_bf16.h>
#include <math.h>

// Problem constants (match reference)
#define NFEAT 512
#define NHID  64
#define NHEADS 8
#define HD    512   // NHEADS*NHID
#define NOUT  64

typedef _Float16 half8 __attribute__((ext_vector_type(8)));
typedef _Float16 half4 __attribute__((ext_vector_type(4)));
typedef float floatx4 __attribute__((ext_vector_type(4)));

// ---------------------------------------------------------------------------
// Kernel 1: fold attention vectors through fW:  G[16][512], C16[16]
// ---------------------------------------------------------------------------
__global__ void g_k(const float* __restrict__ fW_w, const float* __restrict__ fW_b,
                    const float* __restrict__ a_src, const float* __restrict__ a_dest,
                    float* __restrict__ G, float* __restrict__ C16)
{
    int idx = blockIdx.x * blockDim.x + threadIdx.x;
    if (idx < 16 * 512) {
        int r = idx >> 9;       // 0..15
        int f = idx & 511;
        int h = r & 7;
        const float* a = (r < 8) ? a_src : a_dest;
        float s = 0.f;
        #pragma unroll 8
        for (int d = 0; d < 64; ++d)
            s = fmaf(fW_w[(size_t)(h * 64 + d) * 512 + f], a[h * 64 + d], s);
        G[(size_t)r * 512 + f] = s;
    } else if (idx < 16 * 512 + 16) {
        int r = idx - 16 * 512;
        int h = r & 7;
        const float* a = (r < 8) ? a_src : a_dest;
        float s = 0.f;
        for (int d = 0; d < 64; ++d)
            s = fmaf(fW_b[h * 64 + d], a[h * 64 + d], s);
        C16[r] = s;
    }
}

// ---------------------------------------------------------------------------
// Kernel 2: skinny GEMM [N,512] x G^T -> f1[N,8], f2[N,8]; fused feat->fp16.
// ---------------------------------------------------------------------------
#define FB_BM 128
#define FB_BK 64
__global__ __launch_bounds__(256) void f1f2_k(const float* __restrict__ feat,
    const float* __restrict__ G, const float* __restrict__ C16,
    float* __restrict__ f1, float* __restrict__ f2,
    _Float16* __restrict__ featH, int M)
{
    __shared__ float As[FB_BK][FB_BM + 4];
    __shared__ float Gs[16][FB_BK + 1];
    int tid = threadIdx.x;
    int tx = tid & 15;          // output column 0..15
    int ty = tid >> 4;          // 0..15
    int m0 = blockIdx.x * FB_BM;
    float acc[8] = {0.f, 0.f, 0.f, 0.f, 0.f, 0.f, 0.f, 0.f};

    for (int k0 = 0; k0 < NFEAT; k0 += FB_BK) {
        __syncthreads();
        #pragma unroll
        for (int j = 0; j < 8; ++j) {
            int fid = tid + 256 * j;       // 0..2047 float4 slots
            int ml = fid >> 4;             // row 0..127
            int k4 = fid & 15;             // float4 within k-tile
            float4 v = make_float4(0.f, 0.f, 0.f, 0.f);
            int gm = m0 + ml;
            if (gm < M) {
                v = *(const float4*)(feat + (size_t)gm * NFEAT + k0 + k4 * 4);
                half4 hv;
                hv[0] = (_Float16)v.x; hv[1] = (_Float16)v.y;
                hv[2] = (_Float16)v.z; hv[3] = (_Float16)v.w;
                *(half4*)(featH + (size_t)gm * NFEAT + k0 + k4 * 4) = hv;
            }
            As[k4 * 4 + 0][ml] = v.x;
            As[k4 * 4 + 1][ml] = v.y;
            As[k4 * 4 + 2][ml] = v.z;
            As[k4 * 4 + 3][ml] = v.w;
        }
        {
            int gr = tid >> 4;             // 0..15
            int k4 = tid & 15;
            float4 v = *(const float4*)(G + (size_t)gr * 512 + k0 + k4 * 4);
            Gs[gr][k4 * 4 + 0] = v.x;
            Gs[gr][k4 * 4 + 1] = v.y;
            Gs[gr][k4 * 4 + 2] = v.z;
            Gs[gr][k4 * 4 + 3] = v.w;
        }
        __syncthreads();
        #pragma unroll 16
        for (int kk = 0; kk < FB_BK; ++kk) {
            float g = Gs[tx][kk];
            #pragma unroll
            for (int i = 0; i < 8; ++i)
                acc[i] = fmaf(As[kk][ty + 16 * i], g, acc[i]);
        }
    }
    float c = C16[tx];
    #pragma unroll
    for (int i = 0; i < 8; ++i) {
        int gm = m0 + ty + 16 * i;
        if (gm < M) {
            float v = acc[i] + c;
            if (tx < 8) f1[(size_t)gm * 8 + tx] = v;
            else        f2[(size_t)gm * 8 + (tx - 8)] = v;
        }
    }
}

// ---------------------------------------------------------------------------
// CSR build: zero, count, hierarchical scan, fill
// ---------------------------------------------------------------------------
__global__ void zero_k(int* __restrict__ deg, int* __restrict__ fill, int n)
{
    int i = blockIdx.x * blockDim.x + threadIdx.x;
    if (i < n) { deg[i] = 0; fill[i] = 0; }
}

__global__ void count_k(const int* __restrict__ ei, int* __restrict__ deg, int E)
{
    int e = blockIdx.x * blockDim.x + threadIdx.x;
    if (e < E) atomicAdd(&deg[ei[e]], 1);
}

__global__ __launch_bounds__(1024) void bscan_k(const int* __restrict__ deg,
    int* __restrict__ row_ptr, int* __restrict__ bsum, int n)
{
    __shared__ int sh[1024];
    int tid = threadIdx.x;
    int i = blockIdx.x * 1024 + tid;
    int x = (i < n) ? deg[i] : 0;
    sh[tid] = x;
    __syncthreads();
    for (int off = 1; off < 1024; off <<= 1) {
        int v = (tid >= off) ? sh[tid - off] : 0;
        __syncthreads();
        sh[tid] += v;
        __syncthreads();
    }
    if (i < n) row_ptr[i] = sh[tid] - x;    // exclusive within block
    if (tid == 1023) bsum[blockIdx.x] = sh[1023];
}

__global__ void sscan_k(int* __restrict__ bsum, int nb)
{
    if (blockIdx.x == 0 && threadIdx.x == 0) {
        int run = 0;
        for (int b = 0; b < nb; ++b) { int t = bsum[b]; bsum[b] = run; run += t; }
    }
}

__global__ void addoff_k(int* __restrict__ row_ptr, const int* __restrict__ bsum,
                         int n, int Etot)
{
    int i = blockIdx.x * blockDim.x + threadIdx.x;
    if (i < n) row_ptr[i] += bsum[i >> 10];
    if (i == 0) row_ptr[n] = Etot;
}

__global__ void fill_k(const int* __restrict__ ei, const int* __restrict__ row_ptr,
                       int* __restrict__ fill, int* __restrict__ col_s, int E)
{
    int e = blockIdx.x * blockDim.x + threadIdx.x;
    if (e >= E) return;
    int r = ei[e];
    int c = ei[E + e];
    int o = atomicAdd(&fill[r], 1);
    col_s[row_ptr[r] + o] = c;
}

// ---------------------------------------------------------------------------
// Attention: one thread per (row, head). Stores unnormalized exp TRANSPOSED
// [8][E] (head-major) so the head-partitioned agg streams only its own 6.4MB
// slice per XCD, and inv_den transposed [8][N]. (Round-3 lesson: recomputing
// exp in agg loses — the f2 gather misses L2 under the xw gather storm;
// streaming precomputed attn wins.)
// ---------------------------------------------------------------------------
__global__ void attn_k(const int* __restrict__ row_ptr, const int* __restrict__ col_s,
                       const float* __restrict__ f1, const float* __restrict__ f2,
                       float* __restrict__ attn_t, float* __restrict__ inv_t,
                       int n_rows, int E)
{
    int idx = blockIdx.x * blockDim.x + threadIdx.x;
    int n = idx >> 3;
    int h = idx & 7;
    if (n >= n_rows) return;
    int s = row_ptr[n], e = row_ptr[n + 1];
    float F1 = f1[(size_t)n * 8 + h];
    float* at = attn_t + (size_t)h * E;
    float den = 0.f;
    for (int p = s; p < e; ++p) {
        int c = col_s[p];
        float t = F1 + f2[(size_t)c * 8 + h];
        t = (t > 0.f) ? t : 0.2f * t;   // LeakyReLU
        float ex = expf(t);
        den += ex;
        at[p] = ex;
    }
    inv_t[(size_t)h * n_rows + n] = (den > 0.f) ? 1.f / den : 0.f;
}

// ---------------------------------------------------------------------------
// fp32 -> fp16 conversion (n multiple of 8)
// ---------------------------------------------------------------------------
__global__ void cvt_f16_k(const float* __restrict__ in, _Float16* __restrict__ out,
                          size_t n)
{
    size_t i = ((size_t)blockIdx.x * blockDim.x + threadIdx.x) * 8;
    if (i >= n) return;
    float4 a = *(const float4*)(in + i);
    float4 b = *(const float4*)(in + i + 4);
    half8 h;
    h[0] = (_Float16)a.x; h[1] = (_Float16)a.y; h[2] = (_Float16)a.z; h[3] = (_Float16)a.w;
    h[4] = (_Float16)b.x; h[5] = (_Float16)b.y; h[6] = (_Float16)b.z; h[7] = (_Float16)b.w;
    *(half8*)(out + i) = h;
}

// ---------------------------------------------------------------------------
// fp16 MFMA GEMM: A[M,K] * B[N,K]^T + bias -> xw, written HEAD-MAJOR:
// C[head][M][64] with head = global_col/64. This lets the head-partitioned
// agg gather from a per-head 12.8MB table instead of the 102MB [M,512] one.
// 128x128 tile, BK=64, global_load_lds width 16, T2 XOR swizzle via
// pre-swizzled global source (rule #21). Requires K%64==0, N%128==0.
// ---------------------------------------------------------------------------
#define TM 128
#define TN 128
#define TK 64
__global__ __launch_bounds__(256) void gemm_f16_mfma(
    const _Float16* __restrict__ A,   // [M,K]
    const _Float16* __restrict__ B,   // [N,K]
    const float* __restrict__ bias,   // [N]
    _Float16* __restrict__ C,         // [N/64][M][64] head-major
    int M, int N, int K)
{
    __shared__ _Float16 smem_h[TM * TK + TN * TK];   // 32 KB; reused for epilogue
    _Float16* Ash = smem_h;
    _Float16* Bsh = smem_h + TM * TK;
    int tid = threadIdx.x;
    int wave = tid >> 6;
    int lane = tid & 63;
    int m0 = blockIdx.y * TM;      // y = m-panel
    int n0 = blockIdx.x * TN;      // x = n-block (fastest)
    int wm = (wave & 1) * 64;
    int wn = (wave >> 1) * 64;

    floatx4 acc[4][4] = {};

    int fm = lane & 15;
    int q  = lane >> 4;
    int lrow = lane >> 3;                 // 0..7: row within one load instr
    int lcol = (lane & 7) ^ lrow;         // pre-swizzled source col16 slot

    for (int k0 = 0; k0 < K; k0 += TK) {
        __syncthreads();
        #pragma unroll
        for (int t = 0; t < 4; ++t) {
            int r = wave * 8 + t * 32;           // 8 rows per instr, 128 total
            int gr = m0 + r + lrow;
            if (gr > M - 1) gr = M - 1;
            const _Float16* ga = A + (size_t)gr * K + k0 + lcol * 8;
            __builtin_amdgcn_global_load_lds(
                (const __attribute__((address_space(1))) void*)ga,
                (__attribute__((address_space(3))) void*)&Ash[r * TK], 16, 0, 0);
            const _Float16* gb = B + (size_t)(n0 + r + lrow) * K + k0 + lcol * 8;
            __builtin_amdgcn_global_load_lds(
                (const __attribute__((address_space(1))) void*)gb,
                (__attribute__((address_space(3))) void*)&Bsh[r * TK], 16, 0, 0);
        }
        __syncthreads();
        #pragma unroll
        for (int kq = 0; kq < 2; ++kq) {
            half8 af[4], bf[4];
            int sw = ((kq << 2) + q);
            #pragma unroll
            for (int i = 0; i < 4; ++i) {
                int ar = wm + i * 16 + fm;
                af[i] = *(const half8*)&Ash[ar * TK + ((sw ^ (fm & 7)) << 3)];
                int br = wn + i * 16 + fm;
                bf[i] = *(const half8*)&Bsh[br * TK + ((sw ^ (fm & 7)) << 3)];
            }
            #pragma unroll
            for (int i = 0; i < 4; ++i)
                #pragma unroll
                for (int j = 0; j < 4; ++j)
                    acc[i][j] = __builtin_amdgcn_mfma_f32_16x16x32_f16(af[i], bf[j], acc[i][j], 0, 0, 0);
        }
    }
    // Epilogue: per i-subtile (16 rows x 64 cols per wave), stage in LDS with
    // rq-based XOR swizzle (conflict-free), read back coalesced, half8 store.
    // Each wave's 64-col chunk = exactly one head -> head-major store.
    int cn = lane & 15;
    int rq = lane >> 4;               // 0..3
    int head = (n0 + wn) >> 6;
    _Float16* Csh = smem_h + wave * 1024;   // 16*64 halves per wave
    #pragma unroll
    for (int i = 0; i < 4; ++i) {
        __syncthreads();              // protect smem reuse across waves/stages
        #pragma unroll
        for (int j = 0; j < 4; ++j) {
            int col = j * 16 + cn;                  // 0..63
            float bsv = bias[n0 + wn + col];
            int scol = col ^ (rq * 16);             // swizzle: rq picks 16-col block
            #pragma unroll
            for (int r = 0; r < 4; ++r) {
                int row = rq * 4 + r;               // 0..15
                Csh[row * 64 + scol] = (_Float16)(acc[i][j][r] + bsv);
            }
        }
        __syncthreads();
        #pragma unroll
        for (int t = 0; t < 2; ++t) {
            int row = t * 8 + (lane >> 3);          // 0..15
            int c0 = (lane & 7) * 8;                // aligned-8 col run
            int sc0 = c0 ^ (((row >> 2) & 3) * 16); // same swizzle (rq = row>>2)
            half8 v = *(const half8*)&Csh[row * 64 + sc0];
            int gm = m0 + wm + i * 16 + row;
            if (gm < M)
                *(half8*)&C[((size_t)head * M + gm) * 64 + c0] = v;
        }
    }
}

// ---------------------------------------------------------------------------
// fp16 MFMA GEMM, N=64, fp32 out: C[M,64] = A[M,K]*B[64,K]^T + bias
// ---------------------------------------------------------------------------
#define FG_TM 256
#define FG_TK 32
__global__ __launch_bounds__(256) void gemm_f16_n64(
    const _Float16* __restrict__ A,   // [M,K]
    const _Float16* __restrict__ B,   // [64,K]
    const float* __restrict__ bias,   // [64]
    float* __restrict__ C,            // [M,64]
    int M, int K)
{
    __shared__ _Float16 Ash[FG_TM * FG_TK];
    __shared__ _Float16 Bsh[64 * FG_TK];
    int tid = threadIdx.x;
    int wave = tid >> 6;
    int lane = tid & 63;
    int m0 = blockIdx.x * FG_TM;
    int wm = wave * 64;

    floatx4 acc[4][4] = {};
    int fm = lane & 15;
    int q  = lane >> 4;

    for (int k0 = 0; k0 < K; k0 += FG_TK) {
        __syncthreads();
        #pragma unroll
        for (int t = 0; t < 4; ++t) {
            int r = wave * 16 + t * 64;
            int gr = m0 + r + (lane >> 2);
            if (gr > M - 1) gr = M - 1;
            const _Float16* ga = A + (size_t)gr * K + k0 + (lane & 3) * 8;
            __builtin_amdgcn_global_load_lds(
                (const __attribute__((address_space(1))) void*)ga,
                (__attribute__((address_space(3))) void*)&Ash[r * FG_TK], 16, 0, 0);
        }
        {
            int r = wave * 16;
            const _Float16* gb = B + (size_t)(r + (lane >> 2)) * K + k0 + (lane & 3) * 8;
            __builtin_amdgcn_global_load_lds(
                (const __attribute__((address_space(1))) void*)gb,
                (__attribute__((address_space(3))) void*)&Bsh[r * FG_TK], 16, 0, 0);
        }
        __syncthreads();
        half8 af[4], bf[4];
        #pragma unroll
        for (int i = 0; i < 4; ++i) {
            af[i] = *(const half8*)&Ash[(wm + i * 16 + fm) * FG_TK + q * 8];
            bf[i] = *(const half8*)&Bsh[(i * 16 + fm) * FG_TK + q * 8];
        }
        #pragma unroll
        for (int i = 0; i < 4; ++i)
            #pragma unroll
            for (int j = 0; j < 4; ++j)
                acc[i][j] = __builtin_amdgcn_mfma_f32_16x16x32_f16(af[i], bf[j], acc[i][j], 0, 0, 0);
    }
    int cn = lane & 15;
    int rq = lane >> 4;
    #pragma unroll
    for (int i = 0; i < 4; ++i) {
        #pragma unroll
        for (int j = 0; j < 4; ++j) {
            int gn = j * 16 + cn;
            float bsv = bias[gn];
            #pragma unroll
            for (int r = 0; r < 4; ++r) {
                int gm = m0 + wm + i * 16 + rq * 4 + r;
                if (gm < M)
                    C[(size_t)gm * NOUT + gn] = acc[i][j][r] + bsv;
            }
        }
    }
}

// ---------------------------------------------------------------------------
// HEAD-PARTITIONED aggregation. head = blockIdx.x % 8 — hardware assigns
// workgroups to XCDs round-robin, so each XCD processes ONE head and gathers
// from its own 12.8MB per-head table (vs all 8 XCD-L2s replicating the shared
// 102MB table at ~50% miss). Wave per (row,head): lanes = 8 edge-groups x
// 8 ch-slots; 8 edges/iter (each group loads its edge's 128B row chunk);
// one 3-step shfl_xor butterfly per row combines edge-groups.
//   out[n, head*64+ch] = elu( inv * sum_p attn[p]*xw_h[col_p, ch] )
// ---------------------------------------------------------------------------
__global__ __launch_bounds__(256) void agg_h_k(const int* __restrict__ row_ptr,
    const int* __restrict__ col_s, const float* __restrict__ attn_t,
    const float* __restrict__ inv_t, const _Float16* __restrict__ xw,
    _Float16* __restrict__ out, int n_rows, int E)
{
    int head  = blockIdx.x & 7;
    int rowblk = blockIdx.x >> 3;
    int wave  = threadIdx.x >> 6;
    int lane  = threadIdx.x & 63;
    int wid   = rowblk * 4 + wave;
    if (wid >= n_rows) return;
    int s = row_ptr[wid], e = row_ptr[wid + 1];
    int eg = lane >> 3;            // edge group 0..7
    int cs = lane & 7;             // channel slot 0..7 (8 fp16 each)
    const float*    attn_h = attn_t + (size_t)head * E;
    const _Float16* xw_h   = xw + (size_t)head * n_rows * 64;

    float acc[8] = {0.f, 0.f, 0.f, 0.f, 0.f, 0.f, 0.f, 0.f};
    for (int p = s; p < e; p += 8) {
        int pe = p + eg;
        bool act = pe < e;
        int pc = act ? pe : s;
        int c  = col_s[pc];
        float a = act ? attn_h[pe] : 0.f;
        half8 x = *(const half8*)(xw_h + (size_t)c * 64 + cs * 8);
        #pragma unroll
        for (int u = 0; u < 8; ++u)
            acc[u] = fmaf(a, (float)x[u], acc[u]);
    }
    // combine the 8 edge-groups (lanes with same cs, different eg)
    #pragma unroll
    for (int m = 8; m <= 32; m <<= 1) {
        #pragma unroll
        for (int u = 0; u < 8; ++u)
            acc[u] += __shfl_xor(acc[u], m);
    }
    float inv = inv_t[(size_t)head * n_rows + wid];
    half8 o;
    #pragma unroll
    for (int u = 0; u < 8; ++u) {
        float v = acc[u] * inv;
        v = (v > 0.f) ? v : (expf(v) - 1.f);   // ELU
        o[u] = (_Float16)v;
    }
    if (lane < 8)
        __builtin_nontemporal_store(o,
            (half8*)(out + (size_t)wid * HD + head * 64 + lane * 8));
}

// ---------------------------------------------------------------------------
extern "C" void kernel_launch(void* const* d_in, const int* in_sizes, int n_in,
                              void* d_out, int out_size, void* d_ws, size_t ws_size,
                              hipStream_t stream)
{
    const float* feat   = (const float*)d_in[0];
    const int*   ei     = (const int*)  d_in[1];
    const float* fW_w   = (const float*)d_in[2];
    const float* fW_b   = (const float*)d_in[3];
    const float* a_src  = (const float*)d_in[4];
    const float* a_dest = (const float*)d_in[5];
    const float* W0     = (const float*)d_in[6];
    const float* b0     = (const float*)d_in[7];
    const float* W1     = (const float*)d_in[8];
    const float* b1     = (const float*)d_in[9];
    const float* lin_w  = (const float*)d_in[10];
    const float* lin_b  = (const float*)d_in[11];
    float* outp = (float*)d_out;

    const int N = in_sizes[0] / NFEAT;
    const int E = in_sizes[1] / 2;
    const int NB = (N + 1023) / 1024;

    // workspace carve-up (256B aligned)
    char* ws = (char*)d_ws;
    size_t off = 0;
    auto carve = [&](size_t bytes) -> char* {
        char* p = ws + off;
        off += (bytes + 255) & ~(size_t)255;
        return p;
    };
    float*     G       = (float*)carve(16 * 512 * sizeof(float));
    float*     C16     = (float*)carve(16 * sizeof(float));
    float*     f1      = (float*)carve((size_t)N * 8 * sizeof(float));
    float*     f2      = (float*)carve((size_t)N * 8 * sizeof(float));
    int*       deg     = (int*)  carve((size_t)N * sizeof(int));
    int*       fillc   = (int*)  carve((size_t)N * sizeof(int));
    int*       row_ptr = (int*)  carve(((size_t)N + 1) * sizeof(int));
    int*       bsum    = (int*)  carve((size_t)NB * sizeof(int));
    int*       col_s   = (int*)  carve((size_t)E * sizeof(int));
    float*     attn_t  = (float*)carve((size_t)E * 8 * sizeof(float));   // [8][E]
    float*     inv_t   = (float*)carve((size_t)N * 8 * sizeof(float));   // [8][N]
    _Float16*  W0h     = (_Float16*)carve((size_t)HD * NFEAT * sizeof(_Float16));
    _Float16*  W1h     = (_Float16*)carve((size_t)HD * HD * sizeof(_Float16));
    _Float16*  linWh   = (_Float16*)carve((size_t)NOUT * HD * sizeof(_Float16));
    _Float16*  hbuf1   = (_Float16*)carve((size_t)N * NFEAT * sizeof(_Float16)); // featH -> x1H -> x2H
    _Float16*  xwH     = (_Float16*)carve((size_t)N * HD * sizeof(_Float16));    // [8][N][64]
    (void)ws_size; (void)n_in; (void)out_size;

    // 1. fold a_src/a_dest through fW; f1/f2 per node (+ fused feat->fp16)
    g_k<<<(16 * 512 + 16 + 255) / 256, 256, 0, stream>>>(fW_w, fW_b, a_src, a_dest, G, C16);
    f1f2_k<<<(N + FB_BM - 1) / FB_BM, 256, 0, stream>>>(feat, G, C16, f1, f2, hbuf1, N);
    // 2. CSR build
    zero_k<<<(N + 255) / 256, 256, 0, stream>>>(deg, fillc, N);
    count_k<<<(E + 255) / 256, 256, 0, stream>>>(ei, deg, E);
    bscan_k<<<NB, 1024, 0, stream>>>(deg, row_ptr, bsum, N);
    sscan_k<<<1, 64, 0, stream>>>(bsum, NB);
    addoff_k<<<(N + 255) / 256, 256, 0, stream>>>(row_ptr, bsum, N, E);
    fill_k<<<(E + 255) / 256, 256, 0, stream>>>(ei, row_ptr, fillc, col_s, E);
    // 3. per-(row,head) attention: transposed exp [8][E] + inv_den [8][N]
    attn_k<<<((size_t)N * 8 + 255) / 256, 256, 0, stream>>>(row_ptr, col_s, f1, f2, attn_t, inv_t, N, E);

    // 4. weight conversions to fp16
    cvt_f16_k<<<(int)(((size_t)HD * NFEAT / 8 + 255) / 256), 256, 0, stream>>>(W0, W0h, (size_t)HD * NFEAT);
    cvt_f16_k<<<(int)(((size_t)HD * HD / 8 + 255) / 256), 256, 0, stream>>>(W1, W1h, (size_t)HD * HD);
    cvt_f16_k<<<(int)(((size_t)NOUT * HD / 8 + 255) / 256), 256, 0, stream>>>(lin_w, linWh, (size_t)NOUT * HD);

    const int agg_blocks = 8 * ((N + 3) / 4);   // head = bid%8, 4 rows/block

    // 5. layer 0: xw0 = feat @ W0^T + b0 -> xwH (head-major); agg -> hbuf1
    gemm_f16_mfma<<<dim3(HD / TN, (N + TM - 1) / TM), 256, 0, stream>>>(
        hbuf1, W0h, b0, xwH, N, HD, NFEAT);
    agg_h_k<<<agg_blocks, 256, 0, stream>>>(
        row_ptr, col_s, attn_t, inv_t, xwH, hbuf1, N, E);
    // 6. layer 1: xw1 = x1 @ W1^T + b1 -> xwH (head-major); agg -> hbuf1
    gemm_f16_mfma<<<dim3(HD / TN, (N + TM - 1) / TM), 256, 0, stream>>>(
        hbuf1, W1h, b1, xwH, N, HD, HD);
    agg_h_k<<<agg_blocks, 256, 0, stream>>>(
        row_ptr, col_s, attn_t, inv_t, xwH, hbuf1, N, E);
    // 7. final linear (fp16 MFMA, fp32 out) -> d_out
    gemm_f16_n64<<<(N + FG_TM - 1) / FG_TM, 256, 0, stream>>>(
        hbuf1, linWh, lin_b, outp, N, HD);
}

// Round 5
// 1375.389 us; speedup vs baseline: 1.2541x; 1.2541x over previous
//
#include <hip/hip_runtime.h>
#include <hip/hip_bf16.h>
#include <math.h>

// Problem constants (match reference)
#define NFEAT 512
#define NHID  64
#define NHEADS 8
#define HD    512   // NHEADS*NHID
#define NOUT  64

typedef _Float16 half8 __attribute__((ext_vector_type(8)));
typedef _Float16 half4 __attribute__((ext_vector_type(4)));
typedef float floatx4 __attribute__((ext_vector_type(4)));

// ---------------------------------------------------------------------------
// Kernel 1: fold attention vectors through fW:  G[16][512], C16[16]
// ---------------------------------------------------------------------------
__global__ void g_k(const float* __restrict__ fW_w, const float* __restrict__ fW_b,
                    const float* __restrict__ a_src, const float* __restrict__ a_dest,
                    float* __restrict__ G, float* __restrict__ C16)
{
    int idx = blockIdx.x * blockDim.x + threadIdx.x;
    if (idx < 16 * 512) {
        int r = idx >> 9;       // 0..15
        int f = idx & 511;
        int h = r & 7;
        const float* a = (r < 8) ? a_src : a_dest;
        float s = 0.f;
        #pragma unroll 8
        for (int d = 0; d < 64; ++d)
            s = fmaf(fW_w[(size_t)(h * 64 + d) * 512 + f], a[h * 64 + d], s);
        G[(size_t)r * 512 + f] = s;
    } else if (idx < 16 * 512 + 16) {
        int r = idx - 16 * 512;
        int h = r & 7;
        const float* a = (r < 8) ? a_src : a_dest;
        float s = 0.f;
        for (int d = 0; d < 64; ++d)
            s = fmaf(fW_b[h * 64 + d], a[h * 64 + d], s);
        C16[r] = s;
    }
}

// ---------------------------------------------------------------------------
// Kernel 2: skinny GEMM [N,512] x G^T -> f1[N,8], f2[N,8]; fused feat->fp16.
// ---------------------------------------------------------------------------
#define FB_BM 128
#define FB_BK 64
__global__ __launch_bounds__(256) void f1f2_k(const float* __restrict__ feat,
    const float* __restrict__ G, const float* __restrict__ C16,
    float* __restrict__ f1, float* __restrict__ f2,
    _Float16* __restrict__ featH, int M)
{
    __shared__ float As[FB_BK][FB_BM + 4];
    __shared__ float Gs[16][FB_BK + 1];
    int tid = threadIdx.x;
    int tx = tid & 15;          // output column 0..15
    int ty = tid >> 4;          // 0..15
    int m0 = blockIdx.x * FB_BM;
    float acc[8] = {0.f, 0.f, 0.f, 0.f, 0.f, 0.f, 0.f, 0.f};

    for (int k0 = 0; k0 < NFEAT; k0 += FB_BK) {
        __syncthreads();
        #pragma unroll
        for (int j = 0; j < 8; ++j) {
            int fid = tid + 256 * j;       // 0..2047 float4 slots
            int ml = fid >> 4;             // row 0..127
            int k4 = fid & 15;             // float4 within k-tile
            float4 v = make_float4(0.f, 0.f, 0.f, 0.f);
            int gm = m0 + ml;
            if (gm < M) {
                v = *(const float4*)(feat + (size_t)gm * NFEAT + k0 + k4 * 4);
                half4 hv;
                hv[0] = (_Float16)v.x; hv[1] = (_Float16)v.y;
                hv[2] = (_Float16)v.z; hv[3] = (_Float16)v.w;
                *(half4*)(featH + (size_t)gm * NFEAT + k0 + k4 * 4) = hv;
            }
            As[k4 * 4 + 0][ml] = v.x;
            As[k4 * 4 + 1][ml] = v.y;
            As[k4 * 4 + 2][ml] = v.z;
            As[k4 * 4 + 3][ml] = v.w;
        }
        {
            int gr = tid >> 4;             // 0..15
            int k4 = tid & 15;
            float4 v = *(const float4*)(G + (size_t)gr * 512 + k0 + k4 * 4);
            Gs[gr][k4 * 4 + 0] = v.x;
            Gs[gr][k4 * 4 + 1] = v.y;
            Gs[gr][k4 * 4 + 2] = v.z;
            Gs[gr][k4 * 4 + 3] = v.w;
        }
        __syncthreads();
        #pragma unroll 16
        for (int kk = 0; kk < FB_BK; ++kk) {
            float g = Gs[tx][kk];
            #pragma unroll
            for (int i = 0; i < 8; ++i)
                acc[i] = fmaf(As[kk][ty + 16 * i], g, acc[i]);
        }
    }
    float c = C16[tx];
    #pragma unroll
    for (int i = 0; i < 8; ++i) {
        int gm = m0 + ty + 16 * i;
        if (gm < M) {
            float v = acc[i] + c;
            if (tx < 8) f1[(size_t)gm * 8 + tx] = v;
            else        f2[(size_t)gm * 8 + (tx - 8)] = v;
        }
    }
}

// ---------------------------------------------------------------------------
// CSR build: zero, count, hierarchical scan, fill
// ---------------------------------------------------------------------------
__global__ void zero_k(int* __restrict__ deg, int* __restrict__ fill, int n)
{
    int i = blockIdx.x * blockDim.x + threadIdx.x;
    if (i < n) { deg[i] = 0; fill[i] = 0; }
}

__global__ void count_k(const int* __restrict__ ei, int* __restrict__ deg, int E)
{
    int e = blockIdx.x * blockDim.x + threadIdx.x;
    if (e < E) atomicAdd(&deg[ei[e]], 1);
}

__global__ __launch_bounds__(1024) void bscan_k(const int* __restrict__ deg,
    int* __restrict__ row_ptr, int* __restrict__ bsum, int n)
{
    __shared__ int sh[1024];
    int tid = threadIdx.x;
    int i = blockIdx.x * 1024 + tid;
    int x = (i < n) ? deg[i] : 0;
    sh[tid] = x;
    __syncthreads();
    for (int off = 1; off < 1024; off <<= 1) {
        int v = (tid >= off) ? sh[tid - off] : 0;
        __syncthreads();
        sh[tid] += v;
        __syncthreads();
    }
    if (i < n) row_ptr[i] = sh[tid] - x;    // exclusive within block
    if (tid == 1023) bsum[blockIdx.x] = sh[1023];
}

__global__ void sscan_k(int* __restrict__ bsum, int nb)
{
    if (blockIdx.x == 0 && threadIdx.x == 0) {
        int run = 0;
        for (int b = 0; b < nb; ++b) { int t = bsum[b]; bsum[b] = run; run += t; }
    }
}

__global__ void addoff_k(int* __restrict__ row_ptr, const int* __restrict__ bsum,
                         int n, int Etot)
{
    int i = blockIdx.x * blockDim.x + threadIdx.x;
    if (i < n) row_ptr[i] += bsum[i >> 10];
    if (i == 0) row_ptr[n] = Etot;
}

__global__ void fill_k(const int* __restrict__ ei, const int* __restrict__ row_ptr,
                       int* __restrict__ fill, int* __restrict__ col_s, int E)
{
    int e = blockIdx.x * blockDim.x + threadIdx.x;
    if (e >= E) return;
    int r = ei[e];
    int c = ei[E + e];
    int o = atomicAdd(&fill[r], 1);
    col_s[row_ptr[r] + o] = c;
}

// ---------------------------------------------------------------------------
// Attention: one thread per (row, head). Stores unnormalized exp TRANSPOSED
// [8][E] (head-major) so the head-partitioned agg streams only its own 6.4MB
// slice per XCD, and inv_den transposed [8][N].
// ---------------------------------------------------------------------------
__global__ void attn_k(const int* __restrict__ row_ptr, const int* __restrict__ col_s,
                       const float* __restrict__ f1, const float* __restrict__ f2,
                       float* __restrict__ attn_t, float* __restrict__ inv_t,
                       int n_rows, int E)
{
    int idx = blockIdx.x * blockDim.x + threadIdx.x;
    int n = idx >> 3;
    int h = idx & 7;
    if (n >= n_rows) return;
    int s = row_ptr[n], e = row_ptr[n + 1];
    float F1 = f1[(size_t)n * 8 + h];
    float* at = attn_t + (size_t)h * E;
    float den = 0.f;
    for (int p = s; p < e; ++p) {
        int c = col_s[p];
        float t = F1 + f2[(size_t)c * 8 + h];
        t = (t > 0.f) ? t : 0.2f * t;   // LeakyReLU
        float ex = expf(t);
        den += ex;
        at[p] = ex;
    }
    inv_t[(size_t)h * n_rows + n] = (den > 0.f) ? 1.f / den : 0.f;
}

// ---------------------------------------------------------------------------
// fp32 -> fp16 conversion (n multiple of 8)
// ---------------------------------------------------------------------------
__global__ void cvt_f16_k(const float* __restrict__ in, _Float16* __restrict__ out,
                          size_t n)
{
    size_t i = ((size_t)blockIdx.x * blockDim.x + threadIdx.x) * 8;
    if (i >= n) return;
    float4 a = *(const float4*)(in + i);
    float4 b = *(const float4*)(in + i + 4);
    half8 h;
    h[0] = (_Float16)a.x; h[1] = (_Float16)a.y; h[2] = (_Float16)a.z; h[3] = (_Float16)a.w;
    h[4] = (_Float16)b.x; h[5] = (_Float16)b.y; h[6] = (_Float16)b.z; h[7] = (_Float16)b.w;
    *(half8*)(out + i) = h;
}

// ---------------------------------------------------------------------------
// fp16 MFMA GEMM: A[M,K] * B[N,K]^T + bias -> xw, written HEAD-MAJOR:
// C[head][M][64] with head = global_col/64. 128x128 tile, BK=64,
// global_load_lds width 16, T2 XOR swizzle via pre-swizzled global source
// (rule #21). Requires K%64==0, N%128==0.
// ---------------------------------------------------------------------------
#define TM 128
#define TN 128
#define TK 64
__global__ __launch_bounds__(256) void gemm_f16_mfma(
    const _Float16* __restrict__ A,   // [M,K]
    const _Float16* __restrict__ B,   // [N,K]
    const float* __restrict__ bias,   // [N]
    _Float16* __restrict__ C,         // [N/64][M][64] head-major
    int M, int N, int K)
{
    __shared__ _Float16 smem_h[TM * TK + TN * TK];   // 32 KB; reused for epilogue
    _Float16* Ash = smem_h;
    _Float16* Bsh = smem_h + TM * TK;
    int tid = threadIdx.x;
    int wave = tid >> 6;
    int lane = tid & 63;
    int m0 = blockIdx.y * TM;      // y = m-panel
    int n0 = blockIdx.x * TN;      // x = n-block (fastest)
    int wm = (wave & 1) * 64;
    int wn = (wave >> 1) * 64;

    floatx4 acc[4][4] = {};

    int fm = lane & 15;
    int q  = lane >> 4;
    int lrow = lane >> 3;                 // 0..7: row within one load instr
    int lcol = (lane & 7) ^ lrow;         // pre-swizzled source col16 slot

    for (int k0 = 0; k0 < K; k0 += TK) {
        __syncthreads();
        #pragma unroll
        for (int t = 0; t < 4; ++t) {
            int r = wave * 8 + t * 32;           // 8 rows per instr, 128 total
            int gr = m0 + r + lrow;
            if (gr > M - 1) gr = M - 1;
            const _Float16* ga = A + (size_t)gr * K + k0 + lcol * 8;
            __builtin_amdgcn_global_load_lds(
                (const __attribute__((address_space(1))) void*)ga,
                (__attribute__((address_space(3))) void*)&Ash[r * TK], 16, 0, 0);
            const _Float16* gb = B + (size_t)(n0 + r + lrow) * K + k0 + lcol * 8;
            __builtin_amdgcn_global_load_lds(
                (const __attribute__((address_space(1))) void*)gb,
                (__attribute__((address_space(3))) void*)&Bsh[r * TK], 16, 0, 0);
        }
        __syncthreads();
        #pragma unroll
        for (int kq = 0; kq < 2; ++kq) {
            half8 af[4], bf[4];
            int sw = ((kq << 2) + q);
            #pragma unroll
            for (int i = 0; i < 4; ++i) {
                int ar = wm + i * 16 + fm;
                af[i] = *(const half8*)&Ash[ar * TK + ((sw ^ (fm & 7)) << 3)];
                int br = wn + i * 16 + fm;
                bf[i] = *(const half8*)&Bsh[br * TK + ((sw ^ (fm & 7)) << 3)];
            }
            #pragma unroll
            for (int i = 0; i < 4; ++i)
                #pragma unroll
                for (int j = 0; j < 4; ++j)
                    acc[i][j] = __builtin_amdgcn_mfma_f32_16x16x32_f16(af[i], bf[j], acc[i][j], 0, 0, 0);
        }
    }
    // Epilogue: per i-subtile (16 rows x 64 cols per wave), stage in LDS with
    // rq-based XOR swizzle (conflict-free), read back coalesced, half8 store.
    // Each wave's 64-col chunk = exactly one head -> head-major store.
    int cn = lane & 15;
    int rq = lane >> 4;               // 0..3
    int head = (n0 + wn) >> 6;
    _Float16* Csh = smem_h + wave * 1024;   // 16*64 halves per wave
    #pragma unroll
    for (int i = 0; i < 4; ++i) {
        __syncthreads();              // protect smem reuse across waves/stages
        #pragma unroll
        for (int j = 0; j < 4; ++j) {
            int col = j * 16 + cn;                  // 0..63
            float bsv = bias[n0 + wn + col];
            int scol = col ^ (rq * 16);             // swizzle: rq picks 16-col block
            #pragma unroll
            for (int r = 0; r < 4; ++r) {
                int row = rq * 4 + r;               // 0..15
                Csh[row * 64 + scol] = (_Float16)(acc[i][j][r] + bsv);
            }
        }
        __syncthreads();
        #pragma unroll
        for (int t = 0; t < 2; ++t) {
            int row = t * 8 + (lane >> 3);          // 0..15
            int c0 = (lane & 7) * 8;                // aligned-8 col run
            int sc0 = c0 ^ (((row >> 2) & 3) * 16); // same swizzle (rq = row>>2)
            half8 v = *(const half8*)&Csh[row * 64 + sc0];
            int gm = m0 + wm + i * 16 + row;
            if (gm < M)
                *(half8*)&C[((size_t)head * M + gm) * 64 + c0] = v;
        }
    }
}

// ---------------------------------------------------------------------------
// fp16 MFMA GEMM, N=64, fp32 out: C[M,64] = A[M,K]*B[64,K]^T + bias
// ---------------------------------------------------------------------------
#define FG_TM 256
#define FG_TK 32
__global__ __launch_bounds__(256) void gemm_f16_n64(
    const _Float16* __restrict__ A,   // [M,K]
    const _Float16* __restrict__ B,   // [64,K]
    const float* __restrict__ bias,   // [64]
    float* __restrict__ C,            // [M,64]
    int M, int K)
{
    __shared__ _Float16 Ash[FG_TM * FG_TK];
    __shared__ _Float16 Bsh[64 * FG_TK];
    int tid = threadIdx.x;
    int wave = tid >> 6;
    int lane = tid & 63;
    int m0 = blockIdx.x * FG_TM;
    int wm = wave * 64;

    floatx4 acc[4][4] = {};
    int fm = lane & 15;
    int q  = lane >> 4;

    for (int k0 = 0; k0 < K; k0 += FG_TK) {
        __syncthreads();
        #pragma unroll
        for (int t = 0; t < 4; ++t) {
            int r = wave * 16 + t * 64;
            int gr = m0 + r + (lane >> 2);
            if (gr > M - 1) gr = M - 1;
            const _Float16* ga = A + (size_t)gr * K + k0 + (lane & 3) * 8;
            __builtin_amdgcn_global_load_lds(
                (const __attribute__((address_space(1))) void*)ga,
                (__attribute__((address_space(3))) void*)&Ash[r * FG_TK], 16, 0, 0);
        }
        {
            int r = wave * 16;
            const _Float16* gb = B + (size_t)(r + (lane >> 2)) * K + k0 + (lane & 3) * 8;
            __builtin_amdgcn_global_load_lds(
                (const __attribute__((address_space(1))) void*)gb,
                (__attribute__((address_space(3))) void*)&Bsh[r * FG_TK], 16, 0, 0);
        }
        __syncthreads();
        half8 af[4], bf[4];
        #pragma unroll
        for (int i = 0; i < 4; ++i) {
            af[i] = *(const half8*)&Ash[(wm + i * 16 + fm) * FG_TK + q * 8];
            bf[i] = *(const half8*)&Bsh[(i * 16 + fm) * FG_TK + q * 8];
        }
        #pragma unroll
        for (int i = 0; i < 4; ++i)
            #pragma unroll
            for (int j = 0; j < 4; ++j)
                acc[i][j] = __builtin_amdgcn_mfma_f32_16x16x32_f16(af[i], bf[j], acc[i][j], 0, 0, 0);
    }
    int cn = lane & 15;
    int rq = lane >> 4;
    #pragma unroll
    for (int i = 0; i < 4; ++i) {
        #pragma unroll
        for (int j = 0; j < 4; ++j) {
            int gn = j * 16 + cn;
            float bsv = bias[gn];
            #pragma unroll
            for (int r = 0; r < 4; ++r) {
                int gm = m0 + wm + i * 16 + rq * 4 + r;
                if (gm < M)
                    C[(size_t)gm * NOUT + gn] = acc[i][j][r] + bsv;
            }
        }
    }
}

// ---------------------------------------------------------------------------
// HEAD-PARTITIONED aggregation, v2 (no butterfly). head = blockIdx.x % 8 so
// each XCD gathers only from its own 12.8MB per-head table (round-4 measured:
// FETCH 868 -> 615MB). Round-4 lesson: the eg x cs + shfl butterfly shape
// cost ~3x issue slots per row-head; here each 8-LANE GROUP owns one
// (row, head) and walks its edges sequentially — lane = channel slot
// (8 lanes x 16B = the full 128B head-row = 1 L1 transaction), channels are
// lane-private so NO cross-lane reduce, and ELU/store are lane-parallel.
// 2-edge unroll for MLP; TLP (low VGPR, no LDS) hides gather latency.
// ---------------------------------------------------------------------------
__global__ __launch_bounds__(256) void agg_h_k(const int* __restrict__ row_ptr,
    const int* __restrict__ col_s, const float* __restrict__ attn_t,
    const float* __restrict__ inv_t, const _Float16* __restrict__ xw,
    _Float16* __restrict__ out, int n_rows, int E)
{
    int head   = blockIdx.x & 7;
    int rowblk = blockIdx.x >> 3;
    int wave   = threadIdx.x >> 6;
    int lane   = threadIdx.x & 63;
    int row    = rowblk * 32 + wave * 8 + (lane >> 3);
    int cs     = lane & 7;             // channel slot: 8 fp16 = 16B
    const float*    attn_h = attn_t + (size_t)head * E;
    const _Float16* xw_h   = xw + (size_t)head * n_rows * 64;

    bool act = row < n_rows;
    int s = act ? row_ptr[row]     : 0;
    int e = act ? row_ptr[row + 1] : 0;

    float acc0[8] = {0.f, 0.f, 0.f, 0.f, 0.f, 0.f, 0.f, 0.f};
    float acc1[8] = {0.f, 0.f, 0.f, 0.f, 0.f, 0.f, 0.f, 0.f};
    int p = s;
    for (; p + 2 <= e; p += 2) {
        int c0 = col_s[p];
        int c1 = col_s[p + 1];
        float a0 = attn_h[p];
        float a1 = attn_h[p + 1];
        half8 x0 = *(const half8*)(xw_h + (size_t)c0 * 64 + cs * 8);
        half8 x1 = *(const half8*)(xw_h + (size_t)c1 * 64 + cs * 8);
        #pragma unroll
        for (int u = 0; u < 8; ++u) {
            acc0[u] = fmaf(a0, (float)x0[u], acc0[u]);
            acc1[u] = fmaf(a1, (float)x1[u], acc1[u]);
        }
    }
    if (p < e) {
        int c0 = col_s[p];
        float a0 = attn_h[p];
        half8 x0 = *(const half8*)(xw_h + (size_t)c0 * 64 + cs * 8);
        #pragma unroll
        for (int u = 0; u < 8; ++u)
            acc0[u] = fmaf(a0, (float)x0[u], acc0[u]);
    }
    if (!act) return;
    float inv = inv_t[(size_t)head * n_rows + row];
    half8 o;
    #pragma unroll
    for (int u = 0; u < 8; ++u) {
        float v = (acc0[u] + acc1[u]) * inv;
        v = (v > 0.f) ? v : (expf(v) - 1.f);   // ELU
        o[u] = (_Float16)v;
    }
    __builtin_nontemporal_store(o,
        (half8*)(out + (size_t)row * HD + head * 64 + cs * 8));
}

// ---------------------------------------------------------------------------
extern "C" void kernel_launch(void* const* d_in, const int* in_sizes, int n_in,
                              void* d_out, int out_size, void* d_ws, size_t ws_size,
                              hipStream_t stream)
{
    const float* feat   = (const float*)d_in[0];
    const int*   ei     = (const int*)  d_in[1];
    const float* fW_w   = (const float*)d_in[2];
    const float* fW_b   = (const float*)d_in[3];
    const float* a_src  = (const float*)d_in[4];
    const float* a_dest = (const float*)d_in[5];
    const float* W0     = (const float*)d_in[6];
    const float* b0     = (const float*)d_in[7];
    const float* W1     = (const float*)d_in[8];
    const float* b1     = (const float*)d_in[9];
    const float* lin_w  = (const float*)d_in[10];
    const float* lin_b  = (const float*)d_in[11];
    float* outp = (float*)d_out;

    const int N = in_sizes[0] / NFEAT;
    const int E = in_sizes[1] / 2;
    const int NB = (N + 1023) / 1024;

    // workspace carve-up (256B aligned)
    char* ws = (char*)d_ws;
    size_t off = 0;
    auto carve = [&](size_t bytes) -> char* {
        char* p = ws + off;
        off += (bytes + 255) & ~(size_t)255;
        return p;
    };
    float*     G       = (float*)carve(16 * 512 * sizeof(float));
    float*     C16     = (float*)carve(16 * sizeof(float));
    float*     f1      = (float*)carve((size_t)N * 8 * sizeof(float));
    float*     f2      = (float*)carve((size_t)N * 8 * sizeof(float));
    int*       deg     = (int*)  carve((size_t)N * sizeof(int));
    int*       fillc   = (int*)  carve((size_t)N * sizeof(int));
    int*       row_ptr = (int*)  carve(((size_t)N + 1) * sizeof(int));
    int*       bsum    = (int*)  carve((size_t)NB * sizeof(int));
    int*       col_s   = (int*)  carve((size_t)E * sizeof(int));
    float*     attn_t  = (float*)carve((size_t)E * 8 * sizeof(float));   // [8][E]
    float*     inv_t   = (float*)carve((size_t)N * 8 * sizeof(float));   // [8][N]
    _Float16*  W0h     = (_Float16*)carve((size_t)HD * NFEAT * sizeof(_Float16));
    _Float16*  W1h     = (_Float16*)carve((size_t)HD * HD * sizeof(_Float16));
    _Float16*  linWh   = (_Float16*)carve((size_t)NOUT * HD * sizeof(_Float16));
    _Float16*  hbuf1   = (_Float16*)carve((size_t)N * NFEAT * sizeof(_Float16)); // featH -> x1H -> x2H
    _Float16*  xwH     = (_Float16*)carve((size_t)N * HD * sizeof(_Float16));    // [8][N][64]
    (void)ws_size; (void)n_in; (void)out_size;

    // 1. fold a_src/a_dest through fW; f1/f2 per node (+ fused feat->fp16)
    g_k<<<(16 * 512 + 16 + 255) / 256, 256, 0, stream>>>(fW_w, fW_b, a_src, a_dest, G, C16);
    f1f2_k<<<(N + FB_BM - 1) / FB_BM, 256, 0, stream>>>(feat, G, C16, f1, f2, hbuf1, N);
    // 2. CSR build
    zero_k<<<(N + 255) / 256, 256, 0, stream>>>(deg, fillc, N);
    count_k<<<(E + 255) / 256, 256, 0, stream>>>(ei, deg, E);
    bscan_k<<<NB, 1024, 0, stream>>>(deg, row_ptr, bsum, N);
    sscan_k<<<1, 64, 0, stream>>>(bsum, NB);
    addoff_k<<<(N + 255) / 256, 256, 0, stream>>>(row_ptr, bsum, N, E);
    fill_k<<<(E + 255) / 256, 256, 0, stream>>>(ei, row_ptr, fillc, col_s, E);
    // 3. per-(row,head) attention: transposed exp [8][E] + inv_den [8][N]
    attn_k<<<((size_t)N * 8 + 255) / 256, 256, 0, stream>>>(row_ptr, col_s, f1, f2, attn_t, inv_t, N, E);

    // 4. weight conversions to fp16
    cvt_f16_k<<<(int)(((size_t)HD * NFEAT / 8 + 255) / 256), 256, 0, stream>>>(W0, W0h, (size_t)HD * NFEAT);
    cvt_f16_k<<<(int)(((size_t)HD * HD / 8 + 255) / 256), 256, 0, stream>>>(W1, W1h, (size_t)HD * HD);
    cvt_f16_k<<<(int)(((size_t)NOUT * HD / 8 + 255) / 256), 256, 0, stream>>>(lin_w, linWh, (size_t)NOUT * HD);

    const int agg_blocks = 8 * ((N + 31) / 32);   // head = bid%8, 32 rows/block

    // 5. layer 0: xw0 = feat @ W0^T + b0 -> xwH (head-major); agg -> hbuf1
    gemm_f16_mfma<<<dim3(HD / TN, (N + TM - 1) / TM), 256, 0, stream>>>(
        hbuf1, W0h, b0, xwH, N, HD, NFEAT);
    agg_h_k<<<agg_blocks, 256, 0, stream>>>(
        row_ptr, col_s, attn_t, inv_t, xwH, hbuf1, N, E);
    // 6. layer 1: xw1 = x1 @ W1^T + b1 -> xwH (head-major); agg -> hbuf1
    gemm_f16_mfma<<<dim3(HD / TN, (N + TM - 1) / TM), 256, 0, stream>>>(
        hbuf1, W1h, b1, xwH, N, HD, HD);
    agg_h_k<<<agg_blocks, 256, 0, stream>>>(
        row_ptr, col_s, attn_t, inv_t, xwH, hbuf1, N, E);
    // 7. final linear (fp16 MFMA, fp32 out) -> d_out
    gemm_f16_n64<<<(N + FG_TM - 1) / FG_TM, 256, 0, stream>>>(
        hbuf1, linWh, lin_b, outp, N, HD);
}